// Round 2
// baseline (2583.599 us; speedup 1.0000x reference)
//
#include <hip/hip_runtime.h>
#include <stdint.h>

#define NB 2048
#define NW 6
#define ND 1024
#define NH 8
#define NDH 128
#define NTOT 12582912u
#define C_DT 0.09f
#define C_COUP 0.01f
#define C_TOL 0.05f
#define C_THIGH 0.22f
#define NSTEPS 16

struct Flags {
  int done; int prev_done; int apply_noise;
  int cnt_low; int cnt_high; float sum_T;
};

__host__ __device__ __forceinline__ uint32_t rotl32(uint32_t x, uint32_t d) {
  return (x << d) | (x >> (32u - d));
}

// JAX threefry2x32 (20 rounds), matches jax/_src/prng.py
__host__ __device__ __forceinline__ void tf2x32(uint32_t k0, uint32_t k1,
                                                uint32_t x0, uint32_t x1,
                                                uint32_t& o0, uint32_t& o1) {
  const uint32_t k2 = k0 ^ k1 ^ 0x1BD11BDAu;
#define TF_R4(a,b,c,d) \
  x0 += x1; x1 = rotl32(x1,a); x1 ^= x0; \
  x0 += x1; x1 = rotl32(x1,b); x1 ^= x0; \
  x0 += x1; x1 = rotl32(x1,c); x1 ^= x0; \
  x0 += x1; x1 = rotl32(x1,d); x1 ^= x0;
  x0 += k0; x1 += k1;
  TF_R4(13u,15u,26u,6u)  x0 += k1; x1 += k2 + 1u;
  TF_R4(17u,29u,16u,24u) x0 += k2; x1 += k0 + 2u;
  TF_R4(13u,15u,26u,6u)  x0 += k0; x1 += k1 + 3u;
  TF_R4(17u,29u,16u,24u) x0 += k1; x1 += k2 + 4u;
  TF_R4(13u,15u,26u,6u)  x0 += k2; x1 += k0 + 5u;
#undef TF_R4
  o0 = x0; o1 = x1;
}

// XLA ErfInv32 (Giles) polynomial — matches xla/client/lib/math.cc
__device__ __forceinline__ float erfinv_xla(float x) {
  const float w = -log1pf(-x * x);
  float ps, pb;
  const float ws = w - 2.5f;
  ps = 2.81022636e-08f;
  ps = fmaf(ps, ws, 3.43273939e-07f);
  ps = fmaf(ps, ws, -3.5233877e-06f);
  ps = fmaf(ps, ws, -4.39150654e-06f);
  ps = fmaf(ps, ws, 0.00021858087f);
  ps = fmaf(ps, ws, -0.00125372503f);
  ps = fmaf(ps, ws, -0.00417768164f);
  ps = fmaf(ps, ws, 0.246640727f);
  ps = fmaf(ps, ws, 1.50140941f);
  const float wb = sqrtf(w) - 3.0f;
  pb = -0.000200214257f;
  pb = fmaf(pb, wb, 0.000100950558f);
  pb = fmaf(pb, wb, 0.00134934322f);
  pb = fmaf(pb, wb, -0.00367342844f);
  pb = fmaf(pb, wb, 0.00573950773f);
  pb = fmaf(pb, wb, -0.0076224613f);
  pb = fmaf(pb, wb, 0.00943887047f);
  pb = fmaf(pb, wb, 1.00167406f);
  pb = fmaf(pb, wb, 2.83297682f);
  const float p = (w < 5.0f) ? ps : pb;
  return p * x;
}

__device__ __forceinline__ float block_sum(float v, float* red) {
  #pragma unroll
  for (int off = 32; off > 0; off >>= 1) v += __shfl_down(v, off, 64);
  const int t = threadIdx.x;
  __syncthreads();                 // protect red from previous use
  if ((t & 63) == 0) red[t >> 6] = v;
  __syncthreads();
  return red[0] + red[1] + red[2] + red[3];
}

__global__ void init_kernel(Flags* f) {
  f->done = 0; f->prev_done = 0; f->apply_noise = 0;
  f->cnt_low = 0; f->cnt_high = 0; f->sum_T = 0.0f;
}

// M[h][d][e] = sum_r U[h][d][r] * V[h][r][e]
__global__ __launch_bounds__(128) void precompute_M(const float* __restrict__ U,
                                                    const float* __restrict__ V,
                                                    float* __restrict__ M) {
  const int hd = blockIdx.x;          // h*128 + d
  const int h = hd >> 7;
  const int e = threadIdx.x;
  __shared__ float u[64];
  if (e < 64) u[e] = U[hd * 64 + e];
  __syncthreads();
  float acc = 0.0f;
  #pragma unroll
  for (int r = 0; r < 64; ++r)
    acc = fmaf(u[r], V[(h * 64 + r) * 128 + e], acc);
  M[hd * 128 + e] = acc;
}

// One Euler step for batch element b: drift + coupling + signal, clamp_norm,
// write Sn in-place, accumulate tension stats.
__global__ __launch_bounds__(256) void step_kernel(
    const float* __restrict__ Sin, float* __restrict__ Sout,
    const float* __restrict__ signal, const float* __restrict__ M,
    Flags* __restrict__ flags) {
  if (flags->done) return;
  __shared__ __align__(16) float xs[NW][ND];
  __shared__ float mh[NW][NDH];
  __shared__ float red[8];
  const int t = threadIdx.x;
  const int b = blockIdx.x;
  const int e0 = t << 2;              // global element base (4 per thread)
  const int h = t >> 5;               // head owning these 4 elements
  const int el0 = e0 & 127;           // within-head element base

  #pragma unroll
  for (int w = 0; w < NW; ++w) {
    const float4 v = *reinterpret_cast<const float4*>(Sin + (size_t)(b * NW + w) * ND + e0);
    *reinterpret_cast<float4*>(&xs[w][e0]) = v;
  }
  __syncthreads();

  // mean over heads (coupling term), from Sc
  for (int idx = t; idx < NW * NDH; idx += 256) {
    const int w = idx >> 7, el = idx & 127;
    float s = 0.0f;
    #pragma unroll
    for (int hh = 0; hh < NH; ++hh) s += xs[w][hh * NDH + el];
    mh[w][el] = s * 0.125f;
  }
  __syncthreads();

  // acc[w][j] = sum_d x_h[d] * M[h][d][e0+j]   (block reads full M once)
  float acc[NW][4];
  #pragma unroll
  for (int w = 0; w < NW; ++w)
    #pragma unroll
    for (int j = 0; j < 4; ++j) acc[w][j] = 0.0f;

  const float4* Mp = reinterpret_cast<const float4*>(M) + (size_t)(h * NDH) * 32 + (t & 31);
  #pragma unroll 4
  for (int d = 0; d < NDH; ++d) {
    const float4 m = Mp[(size_t)d * 32];
    #pragma unroll
    for (int w = 0; w < NW; ++w) {
      const float xv = xs[w][h * NDH + d];   // broadcast within 32-lane group
      acc[w][0] = fmaf(xv, m.x, acc[w][0]);
      acc[w][1] = fmaf(xv, m.y, acc[w][1]);
      acc[w][2] = fmaf(xv, m.z, acc[w][2]);
      acc[w][3] = fmaf(xv, m.w, acc[w][3]);
    }
  }

  // Euler step: sn = x + DT*(-acc + coup*(mh - x) + signal)   (acc := sn)
  #pragma unroll
  for (int w = 0; w < NW; ++w) {
    const float4 sig = *reinterpret_cast<const float4*>(signal + (size_t)(b * NW + w) * ND + e0);
    const float4 xv4 = *reinterpret_cast<const float4*>(&xs[w][e0]);
    const float sg[4] = {sig.x, sig.y, sig.z, sig.w};
    const float xx[4] = {xv4.x, xv4.y, xv4.z, xv4.w};
    #pragma unroll
    for (int j = 0; j < 4; ++j) {
      const float out = -acc[w][j] + C_COUP * (mh[w][el0 + j] - xx[j]) + sg[j];
      acc[w][j] = fmaf(C_DT, out, xx[j]);
    }
  }

  // clamp_norm per w, write Sn, stash normed rows back into xs
  #pragma unroll 1
  for (int w = 0; w < NW; ++w) {
    const float p = acc[w][0]*acc[w][0] + acc[w][1]*acc[w][1] +
                    acc[w][2]*acc[w][2] + acc[w][3]*acc[w][3];
    const float n2 = block_sum(p, red);   // syncs ensure xs reads are done
    const float n = sqrtf(n2);
    const float scale = fminf(fmaxf(n, 1e-3f), 12.0f) / fmaxf(n, 1e-8f);
    const float inv_norm = 1.0f / (n * scale + 1e-12f);
    float4 o;
    o.x = acc[w][0] * scale; o.y = acc[w][1] * scale;
    o.z = acc[w][2] * scale; o.w = acc[w][3] * scale;
    *reinterpret_cast<float4*>(Sout + (size_t)(b * NW + w) * ND + e0) = o;
    float4 nn;
    nn.x = o.x * inv_norm; nn.y = o.y * inv_norm;
    nn.z = o.z * inv_norm; nn.w = o.w * inv_norm;
    *reinterpret_cast<float4*>(&xs[w][e0]) = nn;
  }
  __syncthreads();

  // tension: mean_dir over W, cos per w, T = 1 - mean_w cos
  float pc[NW];
  #pragma unroll
  for (int w = 0; w < NW; ++w) pc[w] = 0.0f;
  #pragma unroll
  for (int j = 0; j < 4; ++j) {
    float vals[NW];
    float md = 0.0f;
    #pragma unroll
    for (int w = 0; w < NW; ++w) { vals[w] = xs[w][e0 + j]; md += vals[w]; }
    md *= (1.0f / 6.0f);
    #pragma unroll
    for (int w = 0; w < NW; ++w) pc[w] = fmaf(vals[w], md, pc[w]);
  }
  float cos_sum = 0.0f;
  #pragma unroll 1
  for (int w = 0; w < NW; ++w) cos_sum += block_sum(pc[w], red);
  if (t == 0) {
    const float T = 1.0f - cos_sum * (1.0f / 6.0f);
    atomicAdd(&flags->sum_T, T);
    if (T < C_TOL) atomicAdd(&flags->cnt_low, 1);
    if (T > C_THIGH) atomicAdd(&flags->cnt_high, 1);
  }
}

__global__ void flags_kernel(Flags* __restrict__ f, float* __restrict__ trec) {
  const int done_old = f->done;
  const float tmean = f->sum_T * (1.0f / 2048.0f);
  trec[0] = done_old ? __int_as_float(0x7FC00000) : tmean;
  const int nd = (done_old | (f->cnt_low == NB)) ? 1 : 0;
  f->apply_noise = (!nd && (f->cnt_high > 0)) ? 1 : 0;
  f->prev_done = done_old;
  f->done = nd;
  f->sum_T = 0.0f; f->cnt_low = 0; f->cnt_high = 0;
}

// noise kick + renormalize, in place, one (b,w) row per block.
// JAX threefry_partitionable random bits (default since jax 0.4.36):
// per flat element p, counter = 64-bit iota -> (hi=0, lo=p); 32-bit
// output bits = out0 ^ out1.
__global__ __launch_bounds__(256) void noise_kernel(float* __restrict__ S,
                                                    const Flags* __restrict__ flags,
                                                    const uint32_t k0, const uint32_t k1) {
  if (flags->prev_done || !flags->apply_noise) return;
  __shared__ float red[8];
  const int t = threadIdx.x;
  const uint32_t base = (uint32_t)blockIdx.x * ND + (t << 2);
  const float4 s = *reinterpret_cast<const float4*>(S + base);
  float v[4] = {s.x, s.y, s.z, s.w};
  #pragma unroll
  for (int j = 0; j < 4; ++j) {
    const uint32_t p = base + (uint32_t)j;
    uint32_t o0, o1;
    tf2x32(k0, k1, 0u, p, o0, o1);
    const uint32_t bits = o0 ^ o1;
    const float f = __uint_as_float((bits >> 9) | 0x3F800000u) - 1.0f;
    const float lo = -0.99999994f;                // nextafter(-1,0) in f32
    const float u = fmaxf(lo, fmaf(f, 2.0f, lo)); // f*2 exact -> fma == mul+add
    const float z = 1.41421356237f * erfinv_xla(u);
    v[j] = fmaf(0.01f, z, v[j]);
  }
  const float p2 = v[0]*v[0] + v[1]*v[1] + v[2]*v[2] + v[3]*v[3];
  const float n2 = block_sum(p2, red);
  const float inv = 1.0f / (sqrtf(n2) + 1e-8f);
  float4 o;
  o.x = v[0]*inv; o.y = v[1]*inv; o.z = v[2]*inv; o.w = v[3]*inv;
  *reinterpret_cast<float4*>(S + base) = o;
}

extern "C" void kernel_launch(void* const* d_in, const int* in_sizes, int n_in,
                              void* d_out, int out_size, void* d_ws, size_t ws_size,
                              hipStream_t stream) {
  const float* S0     = (const float*)d_in[0];
  const float* signal = (const float*)d_in[1];
  const float* U      = (const float*)d_in[2];
  const float* V      = (const float*)d_in[3];
  float* out   = (float*)d_out;
  float* curve = out + NTOT;
  Flags* flags = (Flags*)d_ws;
  float* M = (float*)((char*)d_ws + 512);   // 512 KB for M, after flags

  init_kernel<<<1, 1, 0, stream>>>(flags);
  precompute_M<<<NH * NDH, 128, 0, stream>>>(U, V, M);

  // fold_in(key(1), k) for k=0..15 on host: threefry((0,1), (0,k))
  uint32_t K0[NSTEPS], K1[NSTEPS];
  for (uint32_t k = 0; k < NSTEPS; ++k) tf2x32(0u, 1u, 0u, k, K0[k], K1[k]);

  for (int k = 0; k < NSTEPS; ++k) {
    step_kernel<<<NB, 256, 0, stream>>>(k == 0 ? S0 : out, out, signal, M, flags);
    flags_kernel<<<1, 1, 0, stream>>>(flags, curve + k);
    noise_kernel<<<NB * NW, 256, 0, stream>>>(out, flags, K0[k], K1[k]);
  }
}